// Round 1
// baseline (144.121 us; speedup 1.0000x reference)
//
#include <hip/hip_runtime.h>

#define TK 80    // TOKEN_DIM
#define TN 384   // EMB_DIM
#define BM 64    // rows per block
#define BN 64    // cols per col-tile
#define NCT 6    // TN / BN
#define LDP 84   // padded LDS stride (84%32=20 -> bank-friendly, keeps float4 align)

// ---------------------------------------------------------------------------
// prep: detect amask storage (bool bytes vs int32), write the three
// passthrough outputs as float32 into the tail of d_out. The normalized
// float mask (0.0/1.0) lands in the amask output slot and is reused by the
// GEMM kernel as its mask input.
// ---------------------------------------------------------------------------
__global__ __launch_bounds__(256) void tok_prep(
    const unsigned char* __restrict__ amask,
    const int* __restrict__ gidx,
    const int* __restrict__ bidx,
    float* __restrict__ out_amask,
    float* __restrict__ out_gidx,
    float* __restrict__ out_bidx,
    int BT, int B)
{
    // Byte-mode detection: read first 256 words. If amask is int32 (0/1),
    // no word has bits above bit 0. If it is packed bool bytes, words look
    // like 0x01000101 etc. -> high bytes set with overwhelming probability.
    const unsigned int* w32 = (const unsigned int*)amask;
    unsigned int w = w32[threadIdx.x & 255];
    int bytemode = __syncthreads_or((int)((w & 0xFFFFFF00u) != 0u));

    int i = blockIdx.x * blockDim.x + threadIdx.x;
    if (i < BT) {
        float m;
        if (bytemode) m = (float)amask[i];
        else          m = (float)(w32[i] & 1u);
        out_amask[i] = m;
        out_bidx[i]  = (float)bidx[i];
        if (i < B) out_gidx[i] = (float)gidx[i];
    }
}

// ---------------------------------------------------------------------------
// GEMM: out[r, e] = mask[r] * (sum_k feat[r,k] * W[e,k] + bias[e])
//       rows r with r % T == 0 (the cls slots, == g_idx) get cls_token.
// Block: 256 threads (16x16), 64-row tile, loops 6 col-tiles of 64.
// Thread tile 4x4, rows ty+16i, cols tx+16j (strided -> conflict-free LDS).
// ---------------------------------------------------------------------------
__global__ __launch_bounds__(256) void tok_gemm(
    const float* __restrict__ feat,
    const float* __restrict__ W,
    const float* __restrict__ bias,
    const float* __restrict__ cls,
    const float* __restrict__ maskf,
    float* __restrict__ out,
    int T)
{
    __shared__ float sA[BM][LDP];
    __shared__ float sB[BN][LDP];

    const int tid = threadIdx.x;
    const int tx = tid & 15;
    const int ty = tid >> 4;
    const int row0 = blockIdx.x * BM;

    // stage feat tile: 64 rows x 80 cols = 1280 float4, 5 per thread
    #pragma unroll
    for (int t = 0; t < 5; ++t) {
        int idx = tid + t * 256;
        int r = idx / 20, c4 = idx % 20;
        float4 v = *(const float4*)(feat + (size_t)(row0 + r) * TK + c4 * 4);
        *(float4*)&sA[r][c4 * 4] = v;
    }

    for (int ct = 0; ct < NCT; ++ct) {
        __syncthreads();   // sA ready (iter 0) / sB reads of prev iter done
        // stage W tile for this col-tile
        #pragma unroll
        for (int t = 0; t < 5; ++t) {
            int idx = tid + t * 256;
            int r = idx / 20, c4 = idx % 20;
            float4 v = *(const float4*)(W + (size_t)(ct * BN + r) * TK + c4 * 4);
            *(float4*)&sB[r][c4 * 4] = v;
        }
        __syncthreads();

        float acc[4][4];
        #pragma unroll
        for (int i2 = 0; i2 < 4; ++i2)
            #pragma unroll
            for (int j = 0; j < 4; ++j) acc[i2][j] = 0.f;

        for (int k4 = 0; k4 < 20; ++k4) {
            float4 a[4], b[4];
            #pragma unroll
            for (int i2 = 0; i2 < 4; ++i2)
                a[i2] = *(const float4*)&sA[ty + 16 * i2][k4 * 4];
            #pragma unroll
            for (int j = 0; j < 4; ++j)
                b[j] = *(const float4*)&sB[tx + 16 * j][k4 * 4];
            #pragma unroll
            for (int i2 = 0; i2 < 4; ++i2) {
                #pragma unroll
                for (int j = 0; j < 4; ++j) {
                    acc[i2][j] += a[i2].x * b[j].x;
                    acc[i2][j] += a[i2].y * b[j].y;
                    acc[i2][j] += a[i2].z * b[j].z;
                    acc[i2][j] += a[i2].w * b[j].w;
                }
            }
        }

        // epilogue
        #pragma unroll
        for (int i2 = 0; i2 < 4; ++i2) {
            int row = row0 + ty + 16 * i2;
            float m = maskf[row];
            bool iscls = (row % T) == 0;
            #pragma unroll
            for (int j = 0; j < 4; ++j) {
                int col = ct * BN + tx + 16 * j;
                float v = m * (acc[i2][j] + bias[col]);
                if (iscls) v = cls[col];
                out[(size_t)row * TN + col] = v;
            }
        }
    }
}

extern "C" void kernel_launch(void* const* d_in, const int* in_sizes, int n_in,
                              void* d_out, int out_size, void* d_ws, size_t ws_size,
                              hipStream_t stream) {
    const float*         feat  = (const float*)d_in[0];
    const unsigned char* amask = (const unsigned char*)d_in[1];
    const int*           gidx  = (const int*)d_in[2];
    const int*           bidx  = (const int*)d_in[3];
    const float*         W     = (const float*)d_in[4];
    const float*         bias  = (const float*)d_in[5];
    const float*         cls   = (const float*)d_in[6];

    const int BT = in_sizes[1];        // B*T rows (131072)
    const int B  = in_sizes[2];        // 16
    const int T  = BT / B;             // 8192

    float* out       = (float*)d_out;                  // [BT, 384]
    float* out_amask = out + (size_t)BT * TN;          // [BT]
    float* out_gidx  = out_amask + BT;                 // [B]
    float* out_bidx  = out_gidx + B;                   // [BT]

    tok_prep<<<(BT + 255) / 256, 256, 0, stream>>>(
        amask, gidx, bidx, out_amask, out_gidx, out_bidx, BT, B);

    tok_gemm<<<BT / BM, 256, 0, stream>>>(
        feat, W, bias, cls, out_amask, out, T);
}

// Round 2
// 58.370 us; speedup vs baseline: 2.4691x; 2.4691x over previous
//
#include <hip/hip_runtime.h>
#include <hip/hip_bf16.h>

#define TK 80    // TOKEN_DIM
#define TN 384   // EMB_DIM
#define BM 64    // rows per block

typedef __attribute__((ext_vector_type(8)))  __bf16 bf16x8;
typedef __attribute__((ext_vector_type(16))) float  f32x16;

// round-to-nearest-even f32 -> bf16 bits
__device__ __forceinline__ unsigned short f2bf_bits(float f) {
    unsigned int u = __float_as_uint(f);
    return (unsigned short)((u + 0x7fffu + ((u >> 16) & 1u)) >> 16);
}

union BF8 { unsigned short u[8]; bf16x8 v; };

__device__ __forceinline__ bf16x8 pack8(float4 f0, float4 f1) {
    BF8 r;
    r.u[0] = f2bf_bits(f0.x); r.u[1] = f2bf_bits(f0.y);
    r.u[2] = f2bf_bits(f0.z); r.u[3] = f2bf_bits(f0.w);
    r.u[4] = f2bf_bits(f1.x); r.u[5] = f2bf_bits(f1.y);
    r.u[6] = f2bf_bits(f1.z); r.u[7] = f2bf_bits(f1.w);
    return r.v;
}

// ---------------------------------------------------------------------------
// prep: detect amask storage (bool bytes vs int32), write the three
// passthrough outputs as float32 into the tail of d_out. The normalized
// float mask (0.0/1.0) lands in the amask output slot and is reused by the
// GEMM kernel as its mask input.
// ---------------------------------------------------------------------------
__global__ __launch_bounds__(256) void tok_prep(
    const unsigned char* __restrict__ amask,
    const int* __restrict__ gidx,
    const int* __restrict__ bidx,
    float* __restrict__ out_amask,
    float* __restrict__ out_gidx,
    float* __restrict__ out_bidx,
    int BT, int B)
{
    const unsigned int* w32 = (const unsigned int*)amask;
    unsigned int w = w32[threadIdx.x & 255];
    int bytemode = __syncthreads_or((int)((w & 0xFFFFFF00u) != 0u));

    int i = blockIdx.x * blockDim.x + threadIdx.x;
    if (i < BT) {
        float m;
        if (bytemode) m = (float)amask[i];
        else          m = (float)(w32[i] & 1u);
        out_amask[i] = m;
        out_bidx[i]  = (float)bidx[i];
        if (i < B) out_gidx[i] = (float)gidx[i];
    }
}

// ---------------------------------------------------------------------------
// MFMA GEMM: out[r,e] = mask[r]*(feat[r,:]@W[e,:] + bias[e]); cls rows get cls.
// Block = 4 waves, 64 rows x 384 cols. Wave w: cols [96w, 96w+96).
// v_mfma_f32_32x32x16_bf16, K = 80 = 5x16 exact. No LDS, no barriers.
// B-frags (W) held in registers for the whole block; A loaded global->reg
// with inline f32->bf16 conversion (each feat byte read once per block,
// block's feat tile = 20 KB -> L1-resident across k-steps).
// ---------------------------------------------------------------------------
__global__ __launch_bounds__(256) void tok_gemm_mfma(
    const float* __restrict__ feat,
    const float* __restrict__ W,
    const float* __restrict__ bias,
    const float* __restrict__ cls,
    const float* __restrict__ maskf,
    float* __restrict__ out,
    int T)
{
    const int lane   = threadIdx.x & 63;
    const int wave   = threadIdx.x >> 6;
    const int row0   = blockIdx.x * BM;
    const int colb   = wave * 96;
    const int lrow   = lane & 31;   // row (A) / col (B,C) within 32-tile
    const int khalf  = lane >> 5;   // which 8-wide k half

    // ---- B fragments: lane holds W[col][ks*16 + khalf*8 .. +7]
    bf16x8 bfrag[3][5];
    #pragma unroll
    for (int nt = 0; nt < 3; ++nt) {
        const float* wrow = W + (size_t)(colb + nt * 32 + lrow) * TK;
        #pragma unroll
        for (int ks = 0; ks < 5; ++ks) {
            const float* p = wrow + ks * 16 + khalf * 8;
            float4 f0 = *(const float4*)p;
            float4 f1 = *(const float4*)(p + 4);
            bfrag[nt][ks] = pack8(f0, f1);
        }
    }

    // ---- mask row vector (one coalesced load, broadcast later via shfl)
    float mv = maskf[row0 + lane];

    // ---- bias / cls per N-tile
    float bv[3], cv[3];
    #pragma unroll
    for (int nt = 0; nt < 3; ++nt) {
        int c = colb + nt * 32 + lrow;
        bv[nt] = bias[c];
        cv[nt] = cls[c];
    }

    // ---- main MFMA loop over K
    f32x16 acc[2][3];
    #pragma unroll
    for (int mt = 0; mt < 2; ++mt)
        #pragma unroll
        for (int nt = 0; nt < 3; ++nt)
            acc[mt][nt] = (f32x16)0.0f;

    #pragma unroll
    for (int ks = 0; ks < 5; ++ks) {
        #pragma unroll
        for (int mt = 0; mt < 2; ++mt) {
            const float* frow = feat + (size_t)(row0 + mt * 32 + lrow) * TK
                              + ks * 16 + khalf * 8;
            float4 f0 = *(const float4*)frow;
            float4 f1 = *(const float4*)(frow + 4);
            bf16x8 a = pack8(f0, f1);
            #pragma unroll
            for (int nt = 0; nt < 3; ++nt)
                acc[mt][nt] = __builtin_amdgcn_mfma_f32_32x32x16_bf16(
                    a, bfrag[nt][ks], acc[mt][nt], 0, 0, 0);
        }
    }

    // ---- epilogue: C/D layout col=lane&31, row=(reg&3)+8*(reg>>2)+4*(lane>>5)
    #pragma unroll
    for (int mt = 0; mt < 2; ++mt) {
        #pragma unroll
        for (int reg = 0; reg < 16; ++reg) {
            int rlocal = mt * 32 + 4 * khalf + (reg & 3) + 8 * (reg >> 2);
            float m = __shfl(mv, rlocal);
            int row = row0 + rlocal;
            bool iscls = (row % T) == 0;
            #pragma unroll
            for (int nt = 0; nt < 3; ++nt) {
                float v = m * (acc[mt][nt][reg] + bv[nt]);
                if (iscls) v = cv[nt];
                out[(size_t)row * TN + colb + nt * 32 + lrow] = v;
            }
        }
    }
}

extern "C" void kernel_launch(void* const* d_in, const int* in_sizes, int n_in,
                              void* d_out, int out_size, void* d_ws, size_t ws_size,
                              hipStream_t stream) {
    const float*         feat  = (const float*)d_in[0];
    const unsigned char* amask = (const unsigned char*)d_in[1];
    const int*           gidx  = (const int*)d_in[2];
    const int*           bidx  = (const int*)d_in[3];
    const float*         W     = (const float*)d_in[4];
    const float*         bias  = (const float*)d_in[5];
    const float*         cls   = (const float*)d_in[6];

    const int BT = in_sizes[1];        // B*T rows (131072)
    const int B  = in_sizes[2];        // 16
    const int T  = BT / B;             // 8192

    float* out       = (float*)d_out;                  // [BT, 384]
    float* out_amask = out + (size_t)BT * TN;          // [BT]
    float* out_gidx  = out_amask + BT;                 // [B]
    float* out_bidx  = out_gidx + B;                   // [BT]

    tok_prep<<<(BT + 255) / 256, 256, 0, stream>>>(
        amask, gidx, bidx, out_amask, out_gidx, out_bidx, BT, B);

    tok_gemm_mfma<<<BT / BM, 256, 0, stream>>>(
        feat, W, bias, cls, out_amask, out, T);
}